// Round 1
// baseline (5603.978 us; speedup 1.0000x reference)
//
#include <hip/hip_runtime.h>
#include <math.h>

#define HID 128
#define EDGE_FEAT 4
#define NUM_G 20
#define N_NODES 20000
#define N_EDGES 640000
#define IN_E (2*HID + EDGE_FEAT + NUM_G)   // 280

__device__ __forceinline__ float silu_f(float v)    { return v / (1.0f + __expf(-v)); }
__device__ __forceinline__ float sigmoid_f(float v) { return 1.0f / (1.0f + __expf(-v)); }

// One 128-thread block per edge. Thread t owns output channel t.
__global__ __launch_bounds__(128) void egnn_edge_kernel(
    const float* __restrict__ h, const float* __restrict__ x,
    const float* __restrict__ edge_attr, const int* __restrict__ edge_index,
    const float* __restrict__ W_e1, const float* __restrict__ b_e1,
    const float* __restrict__ W_e2, const float* __restrict__ b_e2,
    const float* __restrict__ W_g,  const float* __restrict__ b_g,
    const float* __restrict__ W_x1, const float* __restrict__ b_x1,
    const float* __restrict__ W_x2,
    float* __restrict__ agg, float* __restrict__ dxv)
{
    const int e = blockIdx.x;
    const int t = threadIdx.x;

    __shared__ float s_in[IN_E];    // concatenated edge-MLP input
    __shared__ float s_m[HID];      // hidden activations (broadcast)
    __shared__ float s_red[HID];    // reduction scratch
    __shared__ float s_rel[3];
    __shared__ float s_r;

    const int src = edge_index[e];
    const int dst = edge_index[N_EDGES + e];

    // m_in = [h[dst], h[src], d_feat, edge_attr]
    s_in[t]       = h[dst * HID + t];
    s_in[HID + t] = h[src * HID + t];
    if (t == 0) {
        float rx = x[dst*3+0] - x[src*3+0];
        float ry = x[dst*3+1] - x[src*3+1];
        float rz = x[dst*3+2] - x[src*3+2];
        float d2 = rx*rx + ry*ry + rz*rz;
        float r  = sqrtf(d2 + 1e-8f);
        s_rel[0] = rx; s_rel[1] = ry; s_rel[2] = rz;
        s_r = r;
    }
    __syncthreads();
    if (t < NUM_G) {
        const float step  = 10.0f / 19.0f;           // linspace(0,10,20) spacing
        const float coeff = -0.5f / (step * step);
        float d = s_r - step * (float)t;
        s_in[2*HID + t] = __expf(coeff * d * d);
    }
    if (t < EDGE_FEAT) s_in[2*HID + NUM_G + t] = edge_attr[e * EDGE_FEAT + t];
    __syncthreads();

    // layer 1: 280 -> 128, silu
    float acc = b_e1[t];
    #pragma unroll 4
    for (int k = 0; k < IN_E; ++k) acc = fmaf(s_in[k], W_e1[k*HID + t], acc);
    float m1 = silu_f(acc);
    s_m[t] = m1;
    __syncthreads();

    // layer 2: 128 -> 128, silu
    acc = b_e2[t];
    #pragma unroll 4
    for (int k = 0; k < HID; ++k) acc = fmaf(s_m[k], W_e2[k*HID + t], acc);
    float m2 = silu_f(acc);
    __syncthreads();           // everyone done reading s_m(m1)
    s_m[t] = m2;
    __syncthreads();

    // gate: sigmoid(m . W_g + b_g)
    s_red[t] = m2 * W_g[t];
    __syncthreads();
    for (int s = 64; s > 0; s >>= 1) {
        if (t < s) s_red[t] += s_red[t + s];
        __syncthreads();
    }
    const float g = sigmoid_f(s_red[0] + b_g[0]);

    // coordinate head: tanh(silu(m @ W_x1 + b_x1) . W_x2)
    acc = b_x1[t];
    #pragma unroll 4
    for (int k = 0; k < HID; ++k) acc = fmaf(s_m[k], W_x1[k*HID + t], acc);
    float xh = silu_f(acc);
    __syncthreads();           // everyone done with s_red[0] (g)
    s_red[t] = xh * W_x2[t];
    __syncthreads();
    for (int s = 64; s > 0; s >>= 1) {
        if (t < s) s_red[t] += s_red[t + s];
        __syncthreads();
    }
    const float coef = tanhf(s_red[0]);

    // scatter
    atomicAdd(&agg[dst * HID + t], m2 * g);
    if (t < 3) {
        atomicAdd(&dxv[dst * 3 + t], s_rel[t] / (s_r + 1.0f) * coef);
    }
}

// One 128-thread block per node.
__global__ __launch_bounds__(128) void egnn_node_kernel(
    const float* __restrict__ h, const float* __restrict__ x,
    const int* __restrict__ mask,
    const float* __restrict__ W_n1, const float* __restrict__ b_n1,
    const float* __restrict__ W_n2, const float* __restrict__ b_n2,
    const float* __restrict__ agg, const float* __restrict__ dxv,
    float* __restrict__ h_out, float* __restrict__ x_out)
{
    const int n = blockIdx.x;
    const int t = threadIdx.x;

    __shared__ float s_cat[2*HID];
    __shared__ float s_nm[HID];

    s_cat[t]       = agg[n * HID + t];
    s_cat[HID + t] = h[n * HID + t];
    __syncthreads();

    float acc = b_n1[t];
    #pragma unroll 4
    for (int k = 0; k < 2*HID; ++k) acc = fmaf(s_cat[k], W_n1[k*HID + t], acc);
    s_nm[t] = silu_f(acc);
    __syncthreads();

    float acc2 = b_n2[t];
    #pragma unroll 4
    for (int k = 0; k < HID; ++k) acc2 = fmaf(s_nm[k], W_n2[k*HID + t], acc2);

    h_out[n * HID + t] = h[n * HID + t] + acc2;
    if (t < 3) x_out[n * 3 + t] = x[n * 3 + t] + dxv[n * 3 + t] * (float)mask[n];
}

extern "C" void kernel_launch(void* const* d_in, const int* in_sizes, int n_in,
                              void* d_out, int out_size, void* d_ws, size_t ws_size,
                              hipStream_t stream) {
    const float* h          = (const float*)d_in[0];
    const float* x          = (const float*)d_in[1];
    const float* edge_attr  = (const float*)d_in[2];
    const int*   edge_index = (const int*)  d_in[3];
    const int*   mask       = (const int*)  d_in[4];
    const float* W_e1 = (const float*)d_in[5];
    const float* b_e1 = (const float*)d_in[6];
    const float* W_e2 = (const float*)d_in[7];
    const float* b_e2 = (const float*)d_in[8];
    const float* W_g  = (const float*)d_in[9];
    const float* b_g  = (const float*)d_in[10];
    const float* W_n1 = (const float*)d_in[11];
    const float* b_n1 = (const float*)d_in[12];
    const float* W_n2 = (const float*)d_in[13];
    const float* b_n2 = (const float*)d_in[14];
    const float* W_x1 = (const float*)d_in[15];
    const float* b_x1 = (const float*)d_in[16];
    const float* W_x2 = (const float*)d_in[17];

    float* agg = (float*)d_ws;                 // [N_NODES, HID]
    float* dxv = agg + (size_t)N_NODES * HID;  // [N_NODES, 3]

    const size_t zero_bytes = ((size_t)N_NODES * HID + (size_t)N_NODES * 3) * sizeof(float);
    hipMemsetAsync(d_ws, 0, zero_bytes, stream);

    egnn_edge_kernel<<<N_EDGES, 128, 0, stream>>>(
        h, x, edge_attr, edge_index,
        W_e1, b_e1, W_e2, b_e2, W_g, b_g, W_x1, b_x1, W_x2,
        agg, dxv);

    float* h_out = (float*)d_out;                       // [N_NODES, HID]
    float* x_out = h_out + (size_t)N_NODES * HID;       // [N_NODES, 3]

    egnn_node_kernel<<<N_NODES, 128, 0, stream>>>(
        h, x, mask, W_n1, b_n1, W_n2, b_n2, agg, dxv, h_out, x_out);
}

// Round 2
// 831.024 us; speedup vs baseline: 6.7435x; 6.7435x over previous
//
#include <hip/hip_runtime.h>
#include <math.h>

#define HID 128
#define NUM_G 20
#define EF 4
#define NN 20000
#define NE 640000
#define K1 288            // 280 padded to 9*32
#define A1S 296           // LDS stride (bf16 elems) for edge A-tile
#define A2S 136           // LDS stride for 128-col activation tiles
#define KN1 256           // node GEMM1 K
#define AN1S 264          // LDS stride for node A-tile

typedef __attribute__((ext_vector_type(8))) short short8;
typedef __attribute__((ext_vector_type(4))) short short4v;
typedef __attribute__((ext_vector_type(4))) float floatx4;

__device__ __forceinline__ float silu_f(float v){ return v / (1.0f + __expf(-v)); }
__device__ __forceinline__ float sigm_f(float v){ return 1.0f / (1.0f + __expf(-v)); }
// f32 -> bf16 round-to-nearest-even
__device__ __forceinline__ unsigned short f2bf(float v){
    unsigned int u = __float_as_uint(v);
    u = (u + 0x7fffu + ((u >> 16) & 1u)) >> 16;
    return (unsigned short)u;
}

__global__ __launch_bounds__(256) void prep_h_kernel(
    const float* __restrict__ h, unsigned short* __restrict__ h_bf)
{
    int i = (blockIdx.x * 256 + threadIdx.x) * 4;   // 640000 threads cover 2.56M
    float4 v = *(const float4*)(h + i);
    short4v o;
    o[0] = (short)f2bf(v.x); o[1] = (short)f2bf(v.y);
    o[2] = (short)f2bf(v.z); o[3] = (short)f2bf(v.w);
    *(short4v*)(h_bf + i) = o;
}

// transpose + bf16-ify all weight matrices: WT[n][k] = W[k][n]
__global__ __launch_bounds__(320) void prep_w_kernel(
    const float* __restrict__ W_e1, const float* __restrict__ W_e2,
    const float* __restrict__ W_x1, const float* __restrict__ W_n1,
    const float* __restrict__ W_n2,
    unsigned short* __restrict__ WT_e1, unsigned short* __restrict__ WT_e2,
    unsigned short* __restrict__ WT_x1, unsigned short* __restrict__ WT_n1,
    unsigned short* __restrict__ WT_n2)
{
    int n = blockIdx.x;          // 0..127 output channel
    int t = threadIdx.x;         // k index
    if (t < K1)  WT_e1[n*K1  + t] = (t < 280) ? f2bf(W_e1[t*HID + n]) : (unsigned short)0;
    if (t < KN1) WT_n1[n*KN1 + t] = f2bf(W_n1[t*HID + n]);
    if (t < HID) {
        WT_e2[n*HID + t] = f2bf(W_e2[t*HID + n]);
        WT_x1[n*HID + t] = f2bf(W_x1[t*HID + n]);
        WT_n2[n*HID + t] = f2bf(W_n2[t*HID + n]);
    }
}

// 64 edges per block, 256 threads = 4 waves; wave w owns row-tile w (16 edges) x 8 col-tiles.
__global__ __launch_bounds__(256) void egnn_edge_mfma(
    const float* __restrict__ x, const float* __restrict__ edge_attr,
    const int* __restrict__ edge_index,
    const unsigned short* __restrict__ h_bf,
    const unsigned short* __restrict__ WT_e1,
    const unsigned short* __restrict__ WT_e2,
    const unsigned short* __restrict__ WT_x1,
    const float* __restrict__ b_e1, const float* __restrict__ b_e2,
    const float* __restrict__ W_g,  const float* __restrict__ b_g,
    const float* __restrict__ b_x1, const float* __restrict__ W_x2,
    float* __restrict__ agg, float* __restrict__ dxv)
{
    __shared__ __align__(16) unsigned short A1[64*A1S];  // m_in tile (bf16)
    __shared__ __align__(16) unsigned short A2[64*A2S];  // m1 tile
    __shared__ __align__(16) unsigned short A3[64*A2S];  // m2 tile
    __shared__ int   s_dst[64];
    __shared__ int   s_src[64];
    __shared__ float s_rel[64*3];
    __shared__ float s_r[64];

    const int tid  = threadIdx.x;
    const int lane = tid & 63;
    const int wave = tid >> 6;
    const int quad = lane >> 4;
    const int l15  = lane & 15;
    const int e0   = blockIdx.x * 64;

    // per-lane column constants (col = t*16 + l15)
    float be1[8], be2[8], bx1[8], wg[8], wx2[8];
    #pragma unroll
    for (int t = 0; t < 8; ++t) {
        int c = t*16 + l15;
        be1[t] = b_e1[c]; be2[t] = b_e2[c]; bx1[t] = b_x1[c];
        wg[t]  = W_g[c];  wx2[t] = W_x2[c];
    }
    const float bg0 = b_g[0];

    // phase 1: per-edge geometry
    if (tid < 64) {
        int e = e0 + tid;
        int s = edge_index[e];
        int d = edge_index[NE + e];
        s_src[tid] = s; s_dst[tid] = d;
        float rx = x[d*3+0] - x[s*3+0];
        float ry = x[d*3+1] - x[s*3+1];
        float rz = x[d*3+2] - x[s*3+2];
        float r  = sqrtf(rx*rx + ry*ry + rz*rz + 1e-8f);
        s_rel[tid*3+0] = rx; s_rel[tid*3+1] = ry; s_rel[tid*3+2] = rz;
        s_r[tid] = r;
    }
    __syncthreads();

    // phase 2a: gather h rows (cols 0..255), 2048 x 16B jobs
    #pragma unroll
    for (int jj = 0; jj < 8; ++jj) {
        int job  = tid + jj*256;
        int e    = job >> 5;
        int half = (job >> 4) & 1;
        int c16  = job & 15;
        int node = half ? s_src[e] : s_dst[e];
        short8 v = *(const short8*)(h_bf + (size_t)node*HID + c16*8);
        *(short8*)(&A1[e*A1S + half*HID + c16*8]) = v;
    }
    // phase 2b: cols 256..287 (RBF 20 | edge_attr 4 | zero-pad 8)
    const float step  = 10.0f / 19.0f;
    const float coeff = -0.5f / (step*step);
    #pragma unroll
    for (int jj = 0; jj < 8; ++jj) {
        int job = tid + jj*256;
        int e = job >> 5;
        int j = job & 31;
        unsigned short val;
        if (j < NUM_G) {
            float d = s_r[e] - step*(float)j;
            val = f2bf(__expf(coeff*d*d));
        } else if (j < NUM_G+EF) {
            val = f2bf(edge_attr[(size_t)(e0+e)*EF + (j-NUM_G)]);
        } else {
            val = 0;
        }
        A1[e*A1S + 256 + j] = val;
    }
    __syncthreads();

    floatx4 acc[8];

    // GEMM1: [64 x 288] @ [288 x 128], silu -> A2
    #pragma unroll
    for (int t = 0; t < 8; ++t) acc[t] = (floatx4){0.f,0.f,0.f,0.f};
    #pragma unroll
    for (int kc = 0; kc < 9; ++kc) {
        short8 a = *(const short8*)(&A1[(wave*16 + l15)*A1S + kc*32 + quad*8]);
        #pragma unroll
        for (int t = 0; t < 8; ++t) {
            short8 b = *(const short8*)(WT_e1 + (size_t)(t*16+l15)*K1 + kc*32 + quad*8);
            acc[t] = __builtin_amdgcn_mfma_f32_16x16x32_bf16(a, b, acc[t], 0, 0, 0);
        }
    }
    #pragma unroll
    for (int t = 0; t < 8; ++t) {
        int col = t*16 + l15;
        #pragma unroll
        for (int i = 0; i < 4; ++i) {
            int row = wave*16 + quad*4 + i;
            A2[row*A2S + col] = f2bf(silu_f(acc[t][i] + be1[t]));
        }
    }
    __syncthreads();

    // GEMM2: m2 = silu([64x128] @ W_e2 + b), gate, scatter msg, m2 -> A3
    #pragma unroll
    for (int t = 0; t < 8; ++t) acc[t] = (floatx4){0.f,0.f,0.f,0.f};
    #pragma unroll
    for (int kc = 0; kc < 4; ++kc) {
        short8 a = *(const short8*)(&A2[(wave*16 + l15)*A2S + kc*32 + quad*8]);
        #pragma unroll
        for (int t = 0; t < 8; ++t) {
            short8 b = *(const short8*)(WT_e2 + (size_t)(t*16+l15)*HID + kc*32 + quad*8);
            acc[t] = __builtin_amdgcn_mfma_f32_16x16x32_bf16(a, b, acc[t], 0, 0, 0);
        }
    }
    float m2v[8][4];
    float gp[4] = {0.f,0.f,0.f,0.f};
    #pragma unroll
    for (int t = 0; t < 8; ++t)
        #pragma unroll
        for (int i = 0; i < 4; ++i) {
            float m2 = silu_f(acc[t][i] + be2[t]);
            m2v[t][i] = m2;
            gp[i] += m2 * wg[t];
        }
    #pragma unroll
    for (int i = 0; i < 4; ++i) {
        gp[i] += __shfl_xor(gp[i], 1);
        gp[i] += __shfl_xor(gp[i], 2);
        gp[i] += __shfl_xor(gp[i], 4);
        gp[i] += __shfl_xor(gp[i], 8);
        gp[i] = sigm_f(gp[i] + bg0);
    }
    #pragma unroll
    for (int t = 0; t < 8; ++t) {
        int col = t*16 + l15;
        #pragma unroll
        for (int i = 0; i < 4; ++i) {
            int row = wave*16 + quad*4 + i;
            A3[row*A2S + col] = f2bf(m2v[t][i]);
            atomicAdd(&agg[(size_t)s_dst[row]*HID + col], m2v[t][i]*gp[i]);
        }
    }
    __syncthreads();

    // GEMM3: xh = silu(m2 @ W_x1 + b), coef = tanh(xh . W_x2), scatter vec
    #pragma unroll
    for (int t = 0; t < 8; ++t) acc[t] = (floatx4){0.f,0.f,0.f,0.f};
    #pragma unroll
    for (int kc = 0; kc < 4; ++kc) {
        short8 a = *(const short8*)(&A3[(wave*16 + l15)*A2S + kc*32 + quad*8]);
        #pragma unroll
        for (int t = 0; t < 8; ++t) {
            short8 b = *(const short8*)(WT_x1 + (size_t)(t*16+l15)*HID + kc*32 + quad*8);
            acc[t] = __builtin_amdgcn_mfma_f32_16x16x32_bf16(a, b, acc[t], 0, 0, 0);
        }
    }
    float cp[4] = {0.f,0.f,0.f,0.f};
    #pragma unroll
    for (int t = 0; t < 8; ++t)
        #pragma unroll
        for (int i = 0; i < 4; ++i)
            cp[i] += silu_f(acc[t][i] + bx1[t]) * wx2[t];
    #pragma unroll
    for (int i = 0; i < 4; ++i) {
        cp[i] += __shfl_xor(cp[i], 1);
        cp[i] += __shfl_xor(cp[i], 2);
        cp[i] += __shfl_xor(cp[i], 4);
        cp[i] += __shfl_xor(cp[i], 8);
        cp[i] = tanhf(cp[i]);
    }
    if (l15 < 3) {
        #pragma unroll
        for (int i = 0; i < 4; ++i) {
            int row = wave*16 + quad*4 + i;
            float r = s_r[row];
            atomicAdd(&dxv[(size_t)s_dst[row]*3 + l15],
                      s_rel[row*3 + l15] / (r + 1.0f) * cp[i]);
        }
    }
}

// 64 nodes per block; h_out = h + MLP([agg|h]); x_out = x + dxv*mask
__global__ __launch_bounds__(256) void egnn_node_mfma(
    const float* __restrict__ h, const float* __restrict__ x,
    const int* __restrict__ mask,
    const unsigned short* __restrict__ h_bf,
    const float* __restrict__ agg, const float* __restrict__ dxv,
    const unsigned short* __restrict__ WT_n1, const float* __restrict__ b_n1,
    const unsigned short* __restrict__ WT_n2, const float* __restrict__ b_n2,
    float* __restrict__ h_out, float* __restrict__ x_out)
{
    __shared__ __align__(16) unsigned short A1[64*AN1S];
    __shared__ __align__(16) unsigned short A2[64*A2S];

    const int tid  = threadIdx.x;
    const int lane = tid & 63;
    const int wave = tid >> 6;
    const int quad = lane >> 4;
    const int l15  = lane & 15;
    const int n0   = blockIdx.x * 64;

    // x_out epilogue (dxv final by now)
    if (tid < 192) {
        int r = tid / 3, c = tid % 3;
        int n = n0 + r;
        if (n < NN) x_out[n*3 + c] = x[n*3 + c] + dxv[n*3 + c] * (float)mask[n];
    }

    float bn1[8], bn2[8];
    #pragma unroll
    for (int t = 0; t < 8; ++t) {
        int c = t*16 + l15;
        bn1[t] = b_n1[c]; bn2[t] = b_n2[c];
    }

    // stage agg (f32->bf16) cols 0..127: 2048 float4 jobs
    #pragma unroll
    for (int jj = 0; jj < 8; ++jj) {
        int job = tid + jj*256;
        int r = job >> 5;
        int c4 = job & 31;
        int n = n0 + r;
        short4v o;
        if (n < NN) {
            float4 v = *((const float4*)(agg + (size_t)n*HID) + c4);
            o[0] = (short)f2bf(v.x); o[1] = (short)f2bf(v.y);
            o[2] = (short)f2bf(v.z); o[3] = (short)f2bf(v.w);
        } else { o[0]=o[1]=o[2]=o[3]=0; }
        *(short4v*)(&A1[r*AN1S + c4*4]) = o;
    }
    // stage h_bf cols 128..255: 1024 x 16B jobs
    #pragma unroll
    for (int jj = 0; jj < 4; ++jj) {
        int job = tid + jj*256;
        int r = job >> 4;
        int c16 = job & 15;
        int n = n0 + r;
        short8 v;
        if (n < NN) v = *(const short8*)(h_bf + (size_t)n*HID + c16*8);
        else        v = (short8){0,0,0,0,0,0,0,0};
        *(short8*)(&A1[r*AN1S + HID + c16*8]) = v;
    }
    __syncthreads();

    floatx4 acc[8];
    #pragma unroll
    for (int t = 0; t < 8; ++t) acc[t] = (floatx4){0.f,0.f,0.f,0.f};
    #pragma unroll
    for (int kc = 0; kc < 8; ++kc) {
        short8 a = *(const short8*)(&A1[(wave*16 + l15)*AN1S + kc*32 + quad*8]);
        #pragma unroll
        for (int t = 0; t < 8; ++t) {
            short8 b = *(const short8*)(WT_n1 + (size_t)(t*16+l15)*KN1 + kc*32 + quad*8);
            acc[t] = __builtin_amdgcn_mfma_f32_16x16x32_bf16(a, b, acc[t], 0, 0, 0);
        }
    }
    #pragma unroll
    for (int t = 0; t < 8; ++t) {
        int col = t*16 + l15;
        #pragma unroll
        for (int i = 0; i < 4; ++i) {
            int row = wave*16 + quad*4 + i;
            A2[row*A2S + col] = f2bf(silu_f(acc[t][i] + bn1[t]));
        }
    }
    __syncthreads();

    #pragma unroll
    for (int t = 0; t < 8; ++t) acc[t] = (floatx4){0.f,0.f,0.f,0.f};
    #pragma unroll
    for (int kc = 0; kc < 4; ++kc) {
        short8 a = *(const short8*)(&A2[(wave*16 + l15)*A2S + kc*32 + quad*8]);
        #pragma unroll
        for (int t = 0; t < 8; ++t) {
            short8 b = *(const short8*)(WT_n2 + (size_t)(t*16+l15)*HID + kc*32 + quad*8);
            acc[t] = __builtin_amdgcn_mfma_f32_16x16x32_bf16(a, b, acc[t], 0, 0, 0);
        }
    }
    #pragma unroll
    for (int t = 0; t < 8; ++t) {
        int col = t*16 + l15;
        #pragma unroll
        for (int i = 0; i < 4; ++i) {
            int row = wave*16 + quad*4 + i;
            int n = n0 + row;
            if (n < NN)
                h_out[(size_t)n*HID + col] = h[(size_t)n*HID + col] + acc[t][i] + bn2[t];
        }
    }
}

extern "C" void kernel_launch(void* const* d_in, const int* in_sizes, int n_in,
                              void* d_out, int out_size, void* d_ws, size_t ws_size,
                              hipStream_t stream) {
    const float* h          = (const float*)d_in[0];
    const float* x          = (const float*)d_in[1];
    const float* edge_attr  = (const float*)d_in[2];
    const int*   edge_index = (const int*)  d_in[3];
    const int*   mask       = (const int*)  d_in[4];
    const float* W_e1 = (const float*)d_in[5];
    const float* b_e1 = (const float*)d_in[6];
    const float* W_e2 = (const float*)d_in[7];
    const float* b_e2 = (const float*)d_in[8];
    const float* W_g  = (const float*)d_in[9];
    const float* b_g  = (const float*)d_in[10];
    const float* W_n1 = (const float*)d_in[11];
    const float* b_n1 = (const float*)d_in[12];
    const float* W_n2 = (const float*)d_in[13];
    const float* b_n2 = (const float*)d_in[14];
    const float* W_x1 = (const float*)d_in[15];
    const float* b_x1 = (const float*)d_in[16];
    const float* W_x2 = (const float*)d_in[17];

    // workspace layout
    char* ws = (char*)d_ws;
    float* agg = (float*)ws;                       ws += (size_t)NN*HID*4;   // 10.24 MB
    float* dxv = (float*)ws;                       ws += (size_t)NN*3*4;     // 0.24 MB
    unsigned short* h_bf  = (unsigned short*)ws;   ws += (size_t)NN*HID*2;   // 5.12 MB
    unsigned short* WT_e1 = (unsigned short*)ws;   ws += (size_t)HID*K1*2;
    unsigned short* WT_e2 = (unsigned short*)ws;   ws += (size_t)HID*HID*2;
    unsigned short* WT_x1 = (unsigned short*)ws;   ws += (size_t)HID*HID*2;
    unsigned short* WT_n1 = (unsigned short*)ws;   ws += (size_t)HID*KN1*2;
    unsigned short* WT_n2 = (unsigned short*)ws;   ws += (size_t)HID*HID*2;

    hipMemsetAsync(agg, 0, ((size_t)NN*HID + (size_t)NN*3)*sizeof(float), stream);

    prep_h_kernel<<<2500, 256, 0, stream>>>(h, h_bf);
    prep_w_kernel<<<128, 320, 0, stream>>>(W_e1, W_e2, W_x1, W_n1, W_n2,
                                           WT_e1, WT_e2, WT_x1, WT_n1, WT_n2);

    egnn_edge_mfma<<<NE/64, 256, 0, stream>>>(
        x, edge_attr, edge_index, h_bf, WT_e1, WT_e2, WT_x1,
        b_e1, b_e2, W_g, b_g, b_x1, W_x2, agg, dxv);

    float* h_out = (float*)d_out;
    float* x_out = h_out + (size_t)NN*HID;

    egnn_node_mfma<<<(NN + 63)/64, 256, 0, stream>>>(
        h, x, mask, h_bf, agg, dxv, WT_n1, b_n1, WT_n2, b_n2, h_out, x_out);
}